// Round 1
// 264.102 us; speedup vs baseline: 1.1088x; 1.1088x over previous
//
#include <hip/hip_runtime.h>
#include <math.h>

#define DIMK 2048
#define NSEQ 4096
#define NT (DIMK / 64)  // 32 K-tiles of BK=64

typedef short bf16x8 __attribute__((ext_vector_type(8)));
typedef float f32x4 __attribute__((ext_vector_type(4)));
typedef unsigned short u16;

__device__ __forceinline__ u16 f32_to_bf16(float f) {
  unsigned u = __float_as_uint(f);
  u += 0x7fffu + ((u >> 16) & 1u);  // round-to-nearest-even
  return (u16)(u >> 16);
}

__device__ __forceinline__ void async16(const u16* g, u16* l) {
  __builtin_amdgcn_global_load_lds(
      (const __attribute__((address_space(1))) unsigned int*)g,
      (__attribute__((address_space(3))) unsigned int*)l,
      16, 0, 0);
}

// -------- fused fp32 -> bf16 cast for x, Wq, Wk (one launch) --------
__global__ __launch_bounds__(256) void cast3_f32_bf16(
    const float* __restrict__ x, const float* __restrict__ wq,
    const float* __restrict__ wk, u16* __restrict__ xb,
    u16* __restrict__ wqb, u16* __restrict__ wkb) {
  const int xN4 = NSEQ * DIMK / 4;
  const int wN4 = DIMK * DIMK / 4;
  int i = blockIdx.x * 256 + threadIdx.x;
  const float* src;
  u16* dst;
  int j;
  if (i < xN4) { src = x; dst = xb; j = i; }
  else if (i < xN4 + wN4) { src = wq; dst = wqb; j = i - xN4; }
  else { src = wk; dst = wkb; j = i - xN4 - wN4; }
  float4 v = ((const float4*)src)[j];
  ushort4 o;
  o.x = f32_to_bf16(v.x);
  o.y = f32_to_bf16(v.y);
  o.z = f32_to_bf16(v.z);
  o.w = f32_to_bf16(v.w);
  ((ushort4*)dst)[j] = o;
}

// ===================== 256x256 8-phase NT GEMM mainloop =====================
// BM=BN=256, BK=64, 512 threads = 8 waves (2 M-groups x 4 N-groups).
// Per wave: 128x64 output = acc[8][4] f32x4.
// LDS 128 KiB: lds[buf][mat A/B][half 128rows][128*64 bf16], double-buffered.
// Swizzle: 8-bf16 chunk c stored at phys chunk c^(row&7)  (measured 0 bank
// conflicts in the previous kernel; staging pre-swizzles the GLOBAL source so
// global_load_lds dest stays linear — both-sides-or-neither rule).
// Schedule per K-tile = 4 phases x {ds_reads; stage 1 half-tile; [vmcnt];
// s_barrier; lgkmcnt(0); setprio(1); 16 MFMA; setprio(0); s_barrier}.
// Issue order at tile t: p1:[t+1,A-bot]  p2:[t+2,B-top]  p3:[t+2,B-bot]
// p4:[t+2,A-top] + vmcnt(6)  (3 half-tiles stay in flight across barriers).
// Read order: ALL B frags + A-h1 in p1, A-h2 in p3 → every same-buffer
// prefetch targets a region dead for >=1 full barrier. Raw s_barrier only
// (no __syncthreads) so the compiler never drains vmcnt to 0 in the loop.

#define VM6 asm volatile("s_waitcnt vmcnt(6)" ::: "memory")
#define VM4 asm volatile("s_waitcnt vmcnt(4)" ::: "memory")
#define VM0 asm volatile("s_waitcnt vmcnt(0)" ::: "memory")
#define LGKM0 asm volatile("s_waitcnt lgkmcnt(0)" ::: "memory")
#define BAR __builtin_amdgcn_s_barrier()
#define NOOP ((void)0)

#define ISSUE(g, t_, reg)                                 \
  do {                                                    \
    const u16* _gp = (g) + (size_t)(t_) * 64 + stg_goff;  \
    async16(_gp, (reg) + tid * 8);                        \
    async16(_gp + (size_t)64 * DIMK, (reg) + 4096 + tid * 8); \
  } while (0)

#define MF2(i, j, arr)                                                        \
  acc[i][j] = __builtin_amdgcn_mfma_f32_16x16x32_bf16(arr[(i) & 3][0],        \
              bfr[j][0], acc[i][j], 0, 0, 0);                                 \
  acc[i][j] = __builtin_amdgcn_mfma_f32_16x16x32_bf16(arr[(i) & 3][1],        \
              bfr[j][1], acc[i][j], 0, 0, 0);

#define KTILE(bi, S1, S2, S3, S4, VMST)                                   \
  do {                                                                    \
    const u16* _ra = rdA[bi];                                             \
    const u16* _rb = rdB[bi];                                             \
    bf16x8 a1[4][2], a2[4][2], bfr[4][2];                                 \
    _Pragma("unroll") for (int i = 0; i < 4; ++i) {                       \
      a1[i][0] = *(const bf16x8*)&_ra[(i * 16 + fr) * 64 + c0];           \
      a1[i][1] = *(const bf16x8*)&_ra[(i * 16 + fr) * 64 + c1];           \
    }                                                                     \
    _Pragma("unroll") for (int j = 0; j < 4; ++j) {                       \
      bfr[j][0] = *(const bf16x8*)&_rb[(j * 16 + fr) * 64 + c0];          \
      bfr[j][1] = *(const bf16x8*)&_rb[(j * 16 + fr) * 64 + c1];          \
    }                                                                     \
    S1;                                                                   \
    BAR;                                                                  \
    LGKM0;                                                                \
    __builtin_amdgcn_s_setprio(1);                                        \
    MF2(0, 0, a1) MF2(0, 1, a1) MF2(1, 0, a1) MF2(1, 1, a1)               \
    MF2(2, 0, a1) MF2(2, 1, a1) MF2(3, 0, a1) MF2(3, 1, a1)               \
    __builtin_amdgcn_s_setprio(0);                                        \
    BAR;                                                                  \
    S2;                                                                   \
    BAR;                                                                  \
    __builtin_amdgcn_s_setprio(1);                                        \
    MF2(0, 2, a1) MF2(0, 3, a1) MF2(1, 2, a1) MF2(1, 3, a1)               \
    MF2(2, 2, a1) MF2(2, 3, a1) MF2(3, 2, a1) MF2(3, 3, a1)               \
    __builtin_amdgcn_s_setprio(0);                                        \
    BAR;                                                                  \
    _Pragma("unroll") for (int i = 0; i < 4; ++i) {                       \
      a2[i][0] = *(const bf16x8*)&_ra[((i + 4) * 16 + fr) * 64 + c0];     \
      a2[i][1] = *(const bf16x8*)&_ra[((i + 4) * 16 + fr) * 64 + c1];     \
    }                                                                     \
    S3;                                                                   \
    BAR;                                                                  \
    LGKM0;                                                                \
    __builtin_amdgcn_s_setprio(1);                                        \
    MF2(4, 0, a2) MF2(4, 1, a2) MF2(5, 0, a2) MF2(5, 1, a2)               \
    MF2(6, 0, a2) MF2(6, 1, a2) MF2(7, 0, a2) MF2(7, 1, a2)               \
    __builtin_amdgcn_s_setprio(0);                                        \
    BAR;                                                                  \
    S4;                                                                   \
    VMST;                                                                 \
    BAR;                                                                  \
    __builtin_amdgcn_s_setprio(1);                                        \
    MF2(4, 2, a2) MF2(4, 3, a2) MF2(5, 2, a2) MF2(5, 3, a2)               \
    MF2(6, 2, a2) MF2(6, 3, a2) MF2(7, 2, a2) MF2(7, 3, a2)               \
    __builtin_amdgcn_s_setprio(0);                                        \
    BAR;                                                                  \
  } while (0)

__device__ __forceinline__ void mainloop256(
    const u16* __restrict__ A, const u16* __restrict__ B, int rowBase,
    int colBase, u16 (*lds)[2][2][8192], f32x4 acc[8][4]) {
  const int tid = threadIdx.x;
  const int lane = tid & 63;
  const int wid = tid >> 6;
  const int wmg = wid >> 2;  // 0,1 : which 128-row half of A-tile
  const int wng = wid & 3;   // 0..3: which 64-row strip of B-tile
  const int fr = lane & 15;
  const int kq = lane >> 4;

  // staging: thread covers row (tid>>3), phys chunk (tid&7); pre-swizzled
  // global source chunk = (tid&7) ^ (row&7).
  const int stg_goff =
      (tid >> 3) * DIMK + (((tid & 7) ^ ((tid >> 3) & 7)) * 8);
  // frag-read phys chunk offsets (elements) for k-step 0 / 1
  const int c0 = (kq ^ (fr & 7)) * 8;
  const int c1 = ((4 + kq) ^ (fr & 7)) * 8;

  const u16* gA0 = A + (size_t)rowBase * DIMK;
  const u16* gA1 = gA0 + (size_t)128 * DIMK;
  const u16* gB0 = B + (size_t)colBase * DIMK;
  const u16* gB1 = gB0 + (size_t)128 * DIMK;

  u16* sA0[2] = {&lds[0][0][0][0], &lds[1][0][0][0]};
  u16* sA1[2] = {&lds[0][0][1][0], &lds[1][0][1][0]};
  u16* sB0[2] = {&lds[0][1][0][0], &lds[1][1][0][0]};
  u16* sB1[2] = {&lds[0][1][1][0], &lds[1][1][1][0]};

  const u16* rdA[2] = {&lds[0][0][wmg][0], &lds[1][0][wmg][0]};
  const u16* rdB[2] = {&lds[0][1][wng >> 1][(wng & 1) * 4096],
                       &lds[1][1][wng >> 1][(wng & 1) * 4096]};

  // ---- prologue: tile0 fully + 3/4 of tile1; 3 half-tiles left in flight
  ISSUE(gB0, 0, sB0[0]);
  ISSUE(gB1, 0, sB1[0]);
  ISSUE(gA0, 0, sA0[0]);
  ISSUE(gA1, 0, sA1[0]);
  VM4;
  ISSUE(gB0, 1, sB0[1]);
  ISSUE(gB1, 1, sB1[1]);
  ISSUE(gA0, 1, sA0[1]);
  VM6;
  BAR;

#pragma unroll 1
  for (int t = 0; t < NT - 2; t += 2) {
    KTILE(0,
          ISSUE(gA1, t + 1, sA1[1]),   // p1: finish tile t+1 (other buf)
          ISSUE(gB0, t + 2, sB0[0]),   // p2: B-top dead since p1
          ISSUE(gB1, t + 2, sB1[0]),   // p3: B-bot dead since p1
          ISSUE(gA0, t + 2, sA0[0]),   // p4: A-top dead since p3
          VM6);
    KTILE(1,
          ISSUE(gA1, t + 2, sA1[0]),
          ISSUE(gB0, t + 3, sB0[1]),
          ISSUE(gB1, t + 3, sB1[1]),
          ISSUE(gA0, t + 3, sA0[1]),
          VM6);
  }
  // epilogue tiles NT-2 (buf0) and NT-1 (buf1): drain
  KTILE(0, ISSUE(gA1, NT - 1, sA1[1]), NOOP, NOOP, NOOP, VM0);
  KTILE(1, NOOP, NOOP, NOOP, NOOP, NOOP);
}

// -------- GEMM1: Q = x Wq^T + bq ; K = x Wk^T + bk  (z selects) --------
__global__ __launch_bounds__(512) void gemm_qk(
    const u16* __restrict__ X, const u16* __restrict__ Wq,
    const u16* __restrict__ Wk, const float* __restrict__ bq,
    const float* __restrict__ bk, u16* __restrict__ Qo, u16* __restrict__ Ko) {
  __shared__ u16 lds[2][2][2][8192];  // 128 KiB
  const u16* Bmat = blockIdx.z ? Wk : Wq;
  const float* bias = blockIdx.z ? bk : bq;
  u16* Out = blockIdx.z ? Ko : Qo;
  const int rowBase = blockIdx.y * 256;
  const int colBase = blockIdx.x * 256;

  f32x4 acc[8][4] = {};
  mainloop256(X, Bmat, rowBase, colBase, lds, acc);

  const int tid = threadIdx.x;
  const int lane = tid & 63;
  const int wid = tid >> 6;
  const int wmg = wid >> 2;
  const int wng = wid & 3;
  const int fr = lane & 15;
  const int rq = (lane >> 4) * 4;
  const int r0 = rowBase + wmg * 128;
  const int cb = colBase + wng * 64;
#pragma unroll
  for (int j = 0; j < 4; ++j) {
    const int col = cb + j * 16 + fr;
    const float bv = bias[col];
#pragma unroll
    for (int i = 0; i < 8; ++i) {
#pragma unroll
      for (int r = 0; r < 4; ++r) {
        const int row = r0 + i * 16 + rq + r;
        Out[(size_t)row * DIMK + col] = f32_to_bf16(acc[i][j][r] + bv);
      }
    }
  }
}

// -------- GEMM2: scores = scale * Q K^T  (bf16 in, fp32 out) --------
__global__ __launch_bounds__(512) void gemm_scores(
    const u16* __restrict__ Qi, const u16* __restrict__ Ki,
    float* __restrict__ out, float scale) {
  __shared__ u16 lds[2][2][2][8192];
  const int rowBase = blockIdx.y * 256;
  const int colBase = blockIdx.x * 256;

  f32x4 acc[8][4] = {};
  mainloop256(Qi, Ki, rowBase, colBase, lds, acc);

  const int tid = threadIdx.x;
  const int lane = tid & 63;
  const int wid = tid >> 6;
  const int wmg = wid >> 2;
  const int wng = wid & 3;
  const int fr = lane & 15;
  const int rq = (lane >> 4) * 4;
  const int r0 = rowBase + wmg * 128;
  const int cb = colBase + wng * 64;
#pragma unroll
  for (int j = 0; j < 4; ++j) {
    const int col = cb + j * 16 + fr;
#pragma unroll
    for (int i = 0; i < 8; ++i) {
#pragma unroll
      for (int r = 0; r < 4; ++r) {
        const int row = r0 + i * 16 + rq + r;
        out[(size_t)row * NSEQ + col] = acc[i][j][r] * scale;
      }
    }
  }
}

extern "C" void kernel_launch(void* const* d_in, const int* in_sizes, int n_in,
                              void* d_out, int out_size, void* d_ws,
                              size_t ws_size, hipStream_t stream) {
  const float* x = (const float*)d_in[0];
  const float* Wq = (const float*)d_in[1];
  const float* bq = (const float*)d_in[2];
  const float* Wk = (const float*)d_in[3];
  const float* bk = (const float*)d_in[4];
  // d_in[5], d_in[6] (W_v, b_v) unused — V never reaches the output.
  float* out = (float*)d_out;

  // workspace layout (64 MB total)
  u16* xb = (u16*)d_ws;                    // 4096x2048 bf16 (16 MB)
  u16* wqb = xb + (size_t)NSEQ * DIMK;     // 2048x2048 bf16 (8 MB)
  u16* wkb = wqb + (size_t)DIMK * DIMK;    // 8 MB
  u16* qb = wkb + (size_t)DIMK * DIMK;     // 16 MB
  u16* kb = qb + (size_t)NSEQ * DIMK;      // 16 MB

  const int totalN4 = (NSEQ * DIMK + 2 * DIMK * DIMK) / 4;
  cast3_f32_bf16<<<totalN4 / 256, 256, 0, stream>>>(x, Wq, Wk, xb, wqb, wkb);

  gemm_qk<<<dim3(DIMK / 256, NSEQ / 256, 2), 512, 0, stream>>>(xb, wqb, wkb,
                                                               bq, bk, qb, kb);

  const float scale = 1.0f / sqrtf((float)DIMK);
  gemm_scores<<<dim3(NSEQ / 256, NSEQ / 256, 1), 512, 0, stream>>>(qb, kb, out,
                                                                   scale);
}